// Round 4
// baseline (27.882 us; speedup 1.0000x reference)
//
#include <hip/hip_runtime.h>

#define HWX 65536
#define NQ 128      // N (queries)
#define KT 64       // K (targets)
#define CC 134      // classes
#define BB 2        // batch
#define NW 128      // k-windows
#define WIN 512     // floats per window
#define SUB 128     // floats per sub-slice
#define NSUB 4      // sub-slices per window
#define EPSI 1e-5f

typedef __attribute__((ext_vector_type(4))) float f32x4;
typedef __attribute__((ext_vector_type(8))) short bf16x8;
typedef __attribute__((ext_vector_type(4))) unsigned int u32x4;

static __device__ __forceinline__ unsigned int cvtpk(float lo, float hi) {
  unsigned int r;
  asm("v_cvt_pk_bf16_f32 %0, %1, %2" : "=v"(r) : "v"(lo), "v"(hi));
  return r;
}

// lgkmcnt(0) (LDS writes visible) + raw barrier: unlike __syncthreads(),
// does NOT drain vmcnt -> global loads stay in flight across the barrier.
#define BAR()                                                \
  do {                                                       \
    asm volatile("s_waitcnt lgkmcnt(0)" ::: "memory");       \
    __builtin_amdgcn_s_barrier();                            \
  } while (0)

// ---------------- int64-vs-int32 detection (atomic-fallback path only) ------
__global__ void hm_detect(const unsigned int* __restrict__ t,
                          unsigned int* __restrict__ flag) {
  unsigned int w = t[threadIdx.x * 2 + 1];
  unsigned long long any = __ballot(w != 0u);
  if (threadIdx.x == 0) *flag = (any != 0ull) ? 1u : 0u;  // 1 => int32 data
}

// ---------------- stage 1: LDS-staged MFMA over one 512-wide k-window -------
// grid = BB*NW = 256 blocks (1/CU), 512 threads (8 waves).
// 2-deep register pipeline: ISSUE(t+2) -> COMP(t) -> CVTW(t+1) -> BAR, with
// raw barriers so ~96 KB/CU of global loads stay outstanding continuously.
template <bool ATOMIC>
__global__ __launch_bounds__(512)
void hm_stage1(const float* __restrict__ in_mask, const float* __restrict__ tg_mask,
               float* __restrict__ Ipart, float* __restrict__ RSin,
               float* __restrict__ RStg) {
  const int w = blockIdx.x & (NW - 1);
  const int b = blockIdx.x >> 7;
  const int tid = threadIdx.x;
  const int lane = tid & 63;
  const int wv = tid >> 6;            // wave 0..7
  const int srow = tid >> 4;          // staging row group 0..31
  const int scolb = (tid & 15) * 16;  // staging byte col (8 bf16)
  const int l16 = lane & 15;
  const int lg = lane >> 4;

  __shared__ unsigned short lA[2][128 * 128];  // 32 KB x2, XOR-swizzled bf16
  __shared__ unsigned short lB[2][64 * 128];   // 16 KB x2

  const float* Ab = in_mask + (size_t)b * NQ * HWX + (size_t)w * WIN;
  const float* Bb = tg_mask + (size_t)b * KT * HWX + (size_t)w * WIN;

  struct RS { f32x4 a[8]; f32x4 b[4]; };
  RS r0, r1;

  f32x4 acc[4];
  #pragma unroll
  for (int i = 0; i < 4; ++i) acc[i] = f32x4{0.f, 0.f, 0.f, 0.f};
  float rsA[4] = {0.f, 0.f, 0.f, 0.f};
  float rsB[2] = {0.f, 0.f};

  auto ISSUE = [&](RS& r, int t) {
    #pragma unroll
    for (int it = 0; it < 4; ++it) {
      const float* p = Ab + (size_t)(it * 32 + srow) * HWX + t * SUB + (tid & 15) * 8;
      r.a[it * 2]     = *(const f32x4*)p;
      r.a[it * 2 + 1] = *(const f32x4*)(p + 4);
    }
    #pragma unroll
    for (int it = 0; it < 2; ++it) {
      const float* p = Bb + (size_t)(it * 32 + srow) * HWX + t * SUB + (tid & 15) * 8;
      r.b[it * 2]     = *(const f32x4*)p;
      r.b[it * 2 + 1] = *(const f32x4*)(p + 4);
    }
  };

  auto CVTW = [&](RS& r, int buf) {
    char* A8 = (char*)lA[buf];
    char* B8 = (char*)lB[buf];
    #pragma unroll
    for (int it = 0; it < 4; ++it) {
      f32x4 x = r.a[it * 2], y = r.a[it * 2 + 1];
      rsA[it] += (x.x + x.y) + (x.z + x.w) + (y.x + y.y) + (y.z + y.w);
      u32x4 v;
      v.x = cvtpk(x.x, x.y); v.y = cvtpk(x.z, x.w);
      v.z = cvtpk(y.x, y.y); v.w = cvtpk(y.z, y.w);
      const int row = it * 32 + srow;
      *(u32x4*)(A8 + ((row * 256 + scolb) ^ ((row & 7) << 4))) = v;
    }
    #pragma unroll
    for (int it = 0; it < 2; ++it) {
      f32x4 x = r.b[it * 2], y = r.b[it * 2 + 1];
      rsB[it] += (x.x + x.y) + (x.z + x.w) + (y.x + y.y) + (y.z + y.w);
      u32x4 v;
      v.x = cvtpk(x.x, x.y); v.y = cvtpk(x.z, x.w);
      v.z = cvtpk(y.x, y.y); v.w = cvtpk(y.z, y.w);
      const int row = it * 32 + srow;
      *(u32x4*)(B8 + ((row * 256 + scolb) ^ ((row & 7) << 4))) = v;
    }
  };

  auto COMP = [&](int buf) {
    const char* A8 = (const char*)lA[buf];
    const char* B8 = (const char*)lB[buf];
    const int arow = wv * 16 + l16;
    const int sw = (l16 & 7) << 4;
    #pragma unroll
    for (int s = 0; s < 4; ++s) {
      bf16x8 fa = *(const bf16x8*)(A8 + ((arow * 256 + s * 64 + lg * 16) ^ sw));
      #pragma unroll
      for (int cf = 0; cf < 4; ++cf) {
        const int brow = cf * 16 + l16;
        bf16x8 fb = *(const bf16x8*)(B8 + ((brow * 256 + s * 64 + lg * 16) ^ sw));
        acc[cf] = __builtin_amdgcn_mfma_f32_16x16x32_bf16(fa, fb, acc[cf], 0, 0, 0);
      }
    }
  };

  // ---- 2-deep software pipeline over the 4 sub-slices ----------------------
  ISSUE(r0, 0);
  ISSUE(r1, 1);
  CVTW(r0, 0);          // counted vmcnt: waits r0's 12 loads only
  BAR();
  ISSUE(r0, 2);         // in flight across the next two barriers
  COMP(0);
  CVTW(r1, 1);
  BAR();
  ISSUE(r1, 3);
  COMP(1);
  CVTW(r0, 0);
  BAR();
  COMP(0);
  CVTW(r1, 1);
  BAR();
  COMP(1);

  // ---- write intersections (C layout: col = lane&15, row = (lane>>4)*4+j) --
  #pragma unroll
  for (int cf = 0; cf < 4; ++cf) {
    #pragma unroll
    for (int j = 0; j < 4; ++j) {
      const int row = wv * 16 + lg * 4 + j;
      const int col = cf * 16 + l16;
      if (!ATOMIC)
        Ipart[((size_t)(b * NW + w) * NQ + row) * KT + col] = acc[cf][j];
      else
        atomicAdd(&Ipart[((size_t)b * NQ + row) * KT + col], acc[cf][j]);
    }
  }

  // ---- rowsums: reduce across the 16 threads sharing each staged row -------
  #pragma unroll
  for (int it = 0; it < 4; ++it) {
    float v = rsA[it];
    v += __shfl_xor(v, 1); v += __shfl_xor(v, 2);
    v += __shfl_xor(v, 4); v += __shfl_xor(v, 8);
    rsA[it] = v;
  }
  #pragma unroll
  for (int it = 0; it < 2; ++it) {
    float v = rsB[it];
    v += __shfl_xor(v, 1); v += __shfl_xor(v, 2);
    v += __shfl_xor(v, 4); v += __shfl_xor(v, 8);
    rsB[it] = v;
  }
  if ((tid & 15) == 0) {
    if (!ATOMIC) {
      #pragma unroll
      for (int it = 0; it < 4; ++it)
        RSin[(size_t)(b * NW + w) * NQ + it * 32 + srow] = rsA[it];
      #pragma unroll
      for (int it = 0; it < 2; ++it)
        RStg[(size_t)(b * NW + w) * KT + it * 32 + srow] = rsB[it];
    } else {
      #pragma unroll
      for (int it = 0; it < 4; ++it)
        atomicAdd(&RSin[b * NQ + it * 32 + srow], rsA[it]);
      #pragma unroll
      for (int it = 0; it < 2; ++it)
        atomicAdd(&RStg[b * KT + it * 32 + srow], rsB[it]);
    }
  }
}

// ---------------- stage 2 (partial mode): reduce + dice + class gather ------
__global__ __launch_bounds__(256)
void hm_stage2(const float* __restrict__ cprob, const void* __restrict__ tcls,
               const float* __restrict__ Ipart, const float* __restrict__ RSin,
               const float* __restrict__ RStg, float* __restrict__ out) {
  const int bn = blockIdx.x;            // b*NQ + n
  const int b = bn >> 7, n = bn & 127;
  const int k = threadIdx.x & 63;
  const int wq = threadIdx.x >> 6;      // 0..3
  float I = 0.f, ra = 0.f, rg = 0.f;
  #pragma unroll 4
  for (int ww = 0; ww < NW / 4; ++ww) {
    const int w = wq * (NW / 4) + ww;
    I  += Ipart[((size_t)(b * NW + w) * NQ + n) * KT + k];
    ra += RSin[(size_t)(b * NW + w) * NQ + n];
    rg += RStg[(size_t)(b * NW + w) * KT + k];
  }
  __shared__ float sI[4][64];
  __shared__ float sG[4][64];
  __shared__ float sR[4];
  sI[wq][k] = I;
  sG[wq][k] = rg;
  if (k == 0) sR[wq] = ra;
  __syncthreads();
  if (wq == 0) {
    I  = sI[0][k] + sI[1][k] + sI[2][k] + sI[3][k];
    rg = sG[0][k] + sG[1][k] + sG[2][k] + sG[3][k];
    ra = sR[0] + sR[1] + sR[2] + sR[3];
    const unsigned int hi = ((const unsigned int*)tcls)[k * 2 + 1];
    const bool i32 = (__ballot(hi != 0u) != 0ull);
    int tc = i32 ? ((const int*)tcls)[b * KT + k]
                 : (int)((const long long*)tcls)[b * KT + k];
    const float c = cprob[((size_t)b * NQ + n) * CC + tc];
    out[(size_t)bn * KT + k] = c * (2.f * I + EPSI) / (ra + rg + EPSI);
  }
}

// ---------------- stage 2 (atomic fallback mode) ----------------------------
__global__ __launch_bounds__(256)
void hm_stage2_direct(const float* __restrict__ cprob, const void* __restrict__ tcls,
                      const unsigned int* __restrict__ flag,
                      const float* __restrict__ Iacc, const float* __restrict__ RSin,
                      const float* __restrict__ RStg, float* __restrict__ out) {
  const int idx = blockIdx.x * 256 + threadIdx.x;
  const int k = idx & 63;
  const int n = (idx >> 6) & 127;
  const int b = idx >> 13;
  const float I  = Iacc[idx];
  const float ra = RSin[b * NQ + n];
  const float rg = RStg[b * KT + k];
  int tc;
  if (*flag) tc = ((const int*)tcls)[b * KT + k];
  else       tc = (int)((const long long*)tcls)[b * KT + k];
  const float c = cprob[((size_t)b * NQ + n) * CC + tc];
  out[idx] = c * (2.f * I + EPSI) / (ra + rg + EPSI);
}

__global__ void hm_zero(float* __restrict__ p, int n) {
  int i = blockIdx.x * blockDim.x + threadIdx.x;
  if (i < n) p[i] = 0.f;
}

extern "C" void kernel_launch(void* const* d_in, const int* in_sizes, int n_in,
                              void* d_out, int out_size, void* d_ws, size_t ws_size,
                              hipStream_t stream) {
  const float* cprob = (const float*)d_in[0];   // (2,128,134) f32
  const float* imask = (const float*)d_in[1];   // (2,128,65536) f32
  const float* tmask = (const float*)d_in[2];   // (2,64,65536) f32
  const void*  tcls  = d_in[3];                 // (2,64) int64 (or int32)
  float* out = (float*)d_out;                   // (2,128,64) f32

  const size_t ipart_f = (size_t)BB * NW * NQ * KT;  // 2,097,152 floats (8 MB)
  const size_t rsin_f  = (size_t)BB * NW * NQ;       // 32,768
  const size_t rstg_f  = (size_t)BB * NW * KT;       // 16,384
  const size_t need    = (ipart_f + rsin_f + rstg_f) * sizeof(float);

  char* ws = (char*)d_ws;
  if (ws_size >= need) {
    float* Ipart = (float*)ws;
    float* RSin  = Ipart + ipart_f;
    float* RStg  = RSin + rsin_f;
    hm_stage1<false><<<BB * NW, 512, 0, stream>>>(imask, tmask, Ipart, RSin, RStg);
    hm_stage2<<<BB * NQ, 256, 0, stream>>>(cprob, tcls, Ipart, RSin, RStg, out);
  } else {
    // small-scratch atomic fallback (~67 KB)
    float* Iacc = (float*)ws;                     // 16384 floats
    float* RSin = Iacc + (size_t)BB * NQ * KT;    // 256
    float* RStg = RSin + BB * NQ;                 // 128
    unsigned int* flag = (unsigned int*)(RStg + BB * KT);
    const int zn = BB * NQ * KT + BB * NQ + BB * KT;
    hm_zero<<<(zn + 255) / 256, 256, 0, stream>>>(Iacc, zn);
    hm_detect<<<1, 64, 0, stream>>>((const unsigned int*)tcls, flag);
    hm_stage1<true><<<BB * NW, 512, 0, stream>>>(imask, tmask, Iacc, RSin, RStg);
    hm_stage2_direct<<<(BB * NQ * KT) / 256, 256, 0, stream>>>(cprob, tcls, flag, Iacc, RSin, RStg, out);
  }
}